// Round 4
// baseline (428.206 us; speedup 1.0000x reference)
//
#include <hip/hip_runtime.h>

typedef _Float16 f16;
typedef _Float16 f16x8 __attribute__((ext_vector_type(8)));
typedef unsigned short u16x8 __attribute__((ext_vector_type(8)));
typedef float f32x4 __attribute__((ext_vector_type(4)));

#define GLB_AS(p) ((const __attribute__((address_space(1))) unsigned int*)(p))
#define LDS_AS(p) ((__attribute__((address_space(3))) unsigned int*)(p))

// ---------------------------------------------------------------------------
// Kernel S: w_pw fp32 -> fp16 (single rail; threshold 1.25e-2 allows it)
// ---------------------------------------------------------------------------
__global__ __launch_bounds__(256) void whalf(const float* __restrict__ w,
                                             f16* __restrict__ wh) {
  int i = blockIdx.x * 256 + threadIdx.x;  // 65536 total
  wh[i] = (f16)w[i];
}

// ---------------------------------------------------------------------------
// Kernel A: fused depthwise (stage1 3x3 d1 -> branch conv) per channel.
// HT = halo of the *second* conv: 0 (ch 0-63, passthrough), 3 (ch 64-127,
// 3x3 dil3), 6 (ch 128-255, 5x5 dil3).  One block = one (plane, 32x32 tile).
// Writes xc (fp16) planar [b][c][h][w] into Xp (scratch in d_out 2nd half).
// ---------------------------------------------------------------------------
template <int HT>
__global__ __launch_bounds__(256) void dwfuse(
    const float* __restrict__ x, const float* __restrict__ w0,
    const float* __restrict__ b0, const float* __restrict__ w1,
    const float* __restrict__ b1, const float* __restrict__ w2,
    const float* __restrict__ b2, f16* __restrict__ Xp) {
  constexpr int S2 = 32 + 2 * HT;         // t (=x0) tile incl. halo
  constexpr int S1 = S2 + 2;              // x tile incl. halo
  constexpr int PO = (HT == 6) ? 2 : 0;   // pad offset so branch f4 reads align
  constexpr int QW = (S2 + 3) / 4;        // quads per t row
  __shared__ float xs[S1 * 48];
  __shared__ float ts[S2 * 48];
  const int tid = threadIdx.x;

  int b, ch;
  if constexpr (HT == 0) { b = blockIdx.z >> 6; ch = (int)(blockIdx.z & 63); }
  else if constexpr (HT == 3) { b = blockIdx.z >> 6; ch = 64 + (int)(blockIdx.z & 63); }
  else { b = blockIdx.z >> 7; ch = 128 + (int)(blockIdx.z & 127); }
  const int plane = b * 256 + ch;
  const int R0 = (int)blockIdx.y * 32, C0 = (int)blockIdx.x * 32;
  const float* xp = x + (size_t)plane * 16384;

  float W0[9];
#pragma unroll
  for (int k = 0; k < 9; ++k) W0[k] = w0[ch * 9 + k];
  const float B0 = b0[ch];

  // ---- phase 1: load x tile (+halo) into LDS, zero outside image ----
  const int br = R0 - HT - 1, bc = C0 - HT - 1;
  for (int i = tid; i < S1 * S1; i += 256) {
    int r = i / S1, c = i - r * S1;
    int gr = br + r, gc = bc + c;
    float v = 0.f;
    if ((unsigned)gr < 128u && (unsigned)gc < 128u) v = xp[gr * 128 + gc];
    xs[r * 48 + c] = v;
  }
  __syncthreads();

  // ---- phase 2: t = conv3x3(x)+b0 on S2 x S2 (zeroed outside image: x0's
  //      zero-padding semantics for the branch conv) ----
  for (int q = tid; q < S2 * QW; q += 256) {
    int r = q / QW, c4 = (q - r * QW) * 4;
    float a0 = 0, a1 = 0, a2 = 0, a3 = 0;
#pragma unroll
    for (int dy = 0; dy < 3; ++dy) {
      const float* row = &xs[(r + dy) * 48 + c4];
      float4 qa = *(const float4*)row;
      float4 qb = *(const float4*)(row + 4);
      float wA = W0[dy * 3 + 0], wB = W0[dy * 3 + 1], wC = W0[dy * 3 + 2];
      a0 += wA * qa.x + wB * qa.y + wC * qa.z;
      a1 += wA * qa.y + wB * qa.z + wC * qa.w;
      a2 += wA * qa.z + wB * qa.w + wC * qb.x;
      a3 += wA * qa.w + wB * qb.x + wC * qb.y;
    }
    int gr = R0 - HT + r;
    int gc = C0 - HT + c4;
    bool rok = (unsigned)gr < 128u;
    float o0 = (rok && (unsigned)(gc + 0) < 128u) ? a0 + B0 : 0.f;
    float o1 = (rok && (unsigned)(gc + 1) < 128u) ? a1 + B0 : 0.f;
    float o2 = (rok && (unsigned)(gc + 2) < 128u) ? a2 + B0 : 0.f;
    float o3 = (rok && (unsigned)(gc + 3) < 128u) ? a3 + B0 : 0.f;
    float* tp = &ts[r * 48 + c4 + PO];
    tp[0] = o0; tp[1] = o1; tp[2] = o2; tp[3] = o3;
  }
  __syncthreads();

  // ---- phase 3: branch conv, 4 horizontally-adjacent outputs per thread ----
  const int orow = tid >> 3;        // 0..31
  const int oc4 = (tid & 7) << 2;   // 0,4,..,28
  float o0, o1, o2, o3;
  if constexpr (HT == 0) {
    float4 qa = *(const float4*)&ts[orow * 48 + oc4];
    o0 = qa.x; o1 = qa.y; o2 = qa.z; o3 = qa.w;
  } else if constexpr (HT == 3) {
    const int wi = ch & 63;
    float W1[9];
#pragma unroll
    for (int k = 0; k < 9; ++k) W1[k] = w1[wi * 9 + k];
    o0 = o1 = o2 = o3 = b1[wi];
#pragma unroll
    for (int dy = 0; dy < 3; ++dy) {
      const float* row = &ts[(orow + 3 * dy) * 48 + oc4];
      float4 qa = *(const float4*)row;
      float4 qb = *(const float4*)(row + 4);
      float4 qc = *(const float4*)(row + 8);
      float v[12] = {qa.x, qa.y, qa.z, qa.w, qb.x, qb.y, qb.z, qb.w,
                     qc.x, qc.y, qc.z, qc.w};
#pragma unroll
      for (int dx = 0; dx < 3; ++dx) {
        float w = W1[dy * 3 + dx];
        o0 += w * v[3 * dx + 0];
        o1 += w * v[3 * dx + 1];
        o2 += w * v[3 * dx + 2];
        o3 += w * v[3 * dx + 3];
      }
    }
  } else {
    const int wi = ch & 63;   // g2: ch-128, g3: ch-192 -> both = ch&63
    float W2[25];
#pragma unroll
    for (int k = 0; k < 25; ++k) W2[k] = w2[wi * 25 + k];
    o0 = o1 = o2 = o3 = b2[wi];
#pragma unroll
    for (int dy = 0; dy < 5; ++dy) {
      const float* row = &ts[(orow + 3 * dy) * 48 + oc4];
      float4 qa = *(const float4*)(row + 0);
      float4 qb = *(const float4*)(row + 4);
      float4 qc = *(const float4*)(row + 8);
      float4 qd = *(const float4*)(row + 12);
      float4 qe = *(const float4*)(row + 16);
      float v[20] = {qa.x, qa.y, qa.z, qa.w, qb.x, qb.y, qb.z, qb.w,
                     qc.x, qc.y, qc.z, qc.w, qd.x, qd.y, qd.z, qd.w,
                     qe.x, qe.y, qe.z, qe.w};
#pragma unroll
      for (int dx = 0; dx < 5; ++dx) {
        float w = W2[dy * 5 + dx];
        o0 += w * v[3 * dx + 2];
        o1 += w * v[3 * dx + 3];
        o2 += w * v[3 * dx + 4];
        o3 += w * v[3 * dx + 5];
      }
    }
  }
  const size_t oidx =
      (size_t)plane * 16384 + (size_t)(R0 + orow) * 128 + (C0 + oc4);
  union { f16 h[4]; uint2 u; } ph;
  ph.h[0] = (f16)o0; ph.h[1] = (f16)o1; ph.h[2] = (f16)o2; ph.h[3] = (f16)o3;
  *(uint2*)&Xp[oidx] = ph.u;
}

// ---------------------------------------------------------------------------
// Kernel T: transpose xc planar [b][c][16384px] -> XT [b][16384px][256c].
// 64c x 64px tile via LDS (u32 slots, pad-65 => <=2-way banks), coalesced
// 16B loads/stores both sides.
// ---------------------------------------------------------------------------
__global__ __launch_bounds__(256) void t_xpose(const f16* __restrict__ Xp,
                                               f16* __restrict__ XT) {
  __shared__ unsigned ld[64 * 65];
  const int t = threadIdx.x;
  const int b = (int)blockIdx.z, c0 = (int)blockIdx.y << 6,
            p0 = (int)blockIdx.x << 6;
  {
    const int r = t >> 2, ch = (t & 3) << 4;
    const f16* src = Xp + (((size_t)b * 256 + c0 + r) << 14) + p0 + ch;
    u16x8 v0 = *(const u16x8*)src;
    u16x8 v1 = *(const u16x8*)(src + 8);
#pragma unroll
    for (int i = 0; i < 8; ++i) ld[r * 65 + ch + i] = v0[i];
#pragma unroll
    for (int i = 0; i < 8; ++i) ld[r * 65 + ch + 8 + i] = v1[i];
  }
  __syncthreads();
  {
    const int pr = t >> 2, cc = (t & 3) << 4;
    u16x8 w0, w1;
#pragma unroll
    for (int i = 0; i < 8; ++i) w0[i] = (unsigned short)ld[(cc + i) * 65 + pr];
#pragma unroll
    for (int i = 0; i < 8; ++i)
      w1[i] = (unsigned short)ld[(cc + 8 + i) * 65 + pr];
    f16* dst = XT + (((size_t)b * 16384 + p0 + pr) << 8) + c0 + cc;
    *(u16x8*)dst = w0;
    *(u16x8*)(dst + 8) = w1;
  }
}

// ---------------------------------------------------------------------------
// Kernel B: pointwise as fp16 MFMA GEMM, m97 gemm_bt pattern.
// y[o,px] = sum_c W[o,c] * XT[px,c].  Block: 128o x 128px, 4 waves (64x64),
// K=256 in 8 steps of 32.  A = W rows direct from global (L2-hot).
// B = XT tile staged via global_load_lds, linear dest; k-quad slot XOR
// swizzle q = s ^ ((px ^ (px>>2)) & 3) applied on BOTH the pre-swizzled
// global source and the ds_read side (G21).  Bank audit: 8 distinct 128B-mod
// offsets x 2 lanes => 2-way (free, m136).
// ---------------------------------------------------------------------------
__global__ __launch_bounds__(256) void pwgemm(const f16* __restrict__ XT,
                                              const f16* __restrict__ Wh,
                                              const float* __restrict__ bpw,
                                              float* __restrict__ out) {
  __shared__ f16 smem[4096];  // 8 KB: 128 px-rows x 64 B (32 k f16, swizzled)
  const int tid = threadIdx.x, lane = tid & 63, wid = tid >> 6;
  const int bx = (int)blockIdx.x;
  const int nblk = bx >> 1;           // pixel-block; bx pair shares XT tile
  const int m0 = (bx & 1) << 7;       // o-half: 0 or 128
  const int bb = nblk >> 7;           // batch
  const int p0 = (nblk & 127) << 7;   // pixel base within plane

  // staging: LDS byte L = it*4096 + tid*16 -> px = it*64 + (tid>>2),
  // slot s = tid&3 holds k-quad q = s ^ ((px ^ (px>>2)) & 3)
  const int sq = (tid & 3) ^ ((tid >> 2) & 3) ^ ((tid >> 4) & 3);
  const f16* xb0 =
      XT + (((size_t)bb * 16384 + p0 + (tid >> 2)) << 8) + sq * 8;
  const f16* xb1 = xb0 + (64 << 8);  // +64 px rows
  const unsigned lb0 =
      __builtin_amdgcn_readfirstlane((unsigned)(wid * 1024));
  const unsigned lb1 = lb0 + 4096;

  const int wm = (wid >> 1) << 6, wn = (wid & 1) << 6;  // wave 64x64 tile
  const int arow = lane & 15, ak = (lane >> 4) << 3;
  const f16* wrow = Wh + (m0 + wm + arow) * 256 + ak;

  unsigned boff[4];
#pragma unroll
  for (int nf = 0; nf < 4; ++nf) {
    int px = wn + nf * 16 + (lane & 15);
    boff[nf] =
        (unsigned)(px * 64 + ((((lane >> 4) ^ px ^ (px >> 2)) & 3) << 4));
  }

  f32x4 acc[4][4] = {};
  for (int ks = 0; ks < 8; ++ks) {
    __builtin_amdgcn_global_load_lds(GLB_AS(xb0 + ks * 32),
                                     LDS_AS((char*)smem + lb0), 16, 0, 0);
    __builtin_amdgcn_global_load_lds(GLB_AS(xb1 + ks * 32),
                                     LDS_AS((char*)smem + lb1), 16, 0, 0);
    __syncthreads();  // drains vmcnt(0) before s_barrier -> tile visible

    f16x8 a[4], bfr[4];
#pragma unroll
    for (int mf = 0; mf < 4; ++mf)
      a[mf] = *(const f16x8*)(wrow + mf * 16 * 256 + ks * 32);
#pragma unroll
    for (int nf = 0; nf < 4; ++nf)
      bfr[nf] = *(const f16x8*)((const char*)smem + boff[nf]);

#pragma unroll
    for (int mf = 0; mf < 4; ++mf)
#pragma unroll
      for (int nf = 0; nf < 4; ++nf)
        acc[mf][nf] = __builtin_amdgcn_mfma_f32_16x16x32_f16(
            a[mf], bfr[nf], acc[mf][nf], 0, 0, 0);
    __syncthreads();  // all waves done reading before next stage overwrites
  }

  // ---- epilogue: D[row=o][col=px], row=(lane>>4)*4+r, col=lane&15 ----
  float brow[4][4];
#pragma unroll
  for (int mf = 0; mf < 4; ++mf)
#pragma unroll
    for (int r = 0; r < 4; ++r)
      brow[mf][r] = bpw[m0 + wm + mf * 16 + ((lane >> 4) << 2) + r];

  float* op = out + (size_t)bb * 4194304;
#pragma unroll
  for (int mf = 0; mf < 4; ++mf) {
    const int o = m0 + wm + mf * 16 + ((lane >> 4) << 2);
#pragma unroll
    for (int nf = 0; nf < 4; ++nf) {
      const int px = p0 + wn + nf * 16 + (lane & 15);
#pragma unroll
      for (int r = 0; r < 4; ++r)
        op[(size_t)(o + r) * 16384 + px] = acc[mf][nf][r] + brow[mf][r];
    }
  }
}

// ---------------------------------------------------------------------------
extern "C" void kernel_launch(void* const* d_in, const int* in_sizes, int n_in,
                              void* d_out, int out_size, void* d_ws,
                              size_t ws_size, hipStream_t stream) {
  const float* x = (const float*)d_in[0];
  const float* w0 = (const float*)d_in[1];
  const float* b0 = (const float*)d_in[2];
  const float* w1 = (const float*)d_in[3];
  const float* b1 = (const float*)d_in[4];
  const float* w2 = (const float*)d_in[5];
  const float* b2 = (const float*)d_in[6];
  const float* wpw = (const float*)d_in[7];
  const float* bpw = (const float*)d_in[8];
  float* out = (float*)d_out;

  // scratch plan (ws need: 64.125 MiB):
  //   Xp (planar fp16 xc, 64 MiB)  -> d_out second half (read only by t_xpose,
  //                                    which completes before pwgemm writes)
  //   XT (transposed fp16, 64 MiB) -> ws[0:64M]
  //   Wh (fp16 w_pw, 128 KiB)      -> ws[64M:]
  f16* Xp = (f16*)((char*)d_out + 67108864);
  f16* XT = (f16*)d_ws;
  f16* Wh = (f16*)((char*)d_ws + 67108864);

  whalf<<<256, 256, 0, stream>>>(wpw, Wh);
  dwfuse<0><<<dim3(4, 4, 512), 256, 0, stream>>>(x, w0, b0, w1, b1, w2, b2, Xp);
  dwfuse<3><<<dim3(4, 4, 512), 256, 0, stream>>>(x, w0, b0, w1, b1, w2, b2, Xp);
  dwfuse<6><<<dim3(4, 4, 1024), 256, 0, stream>>>(x, w0, b0, w1, b1, w2, b2,
                                                  Xp);
  t_xpose<<<dim3(256, 4, 8), 256, 0, stream>>>(Xp, XT);
  pwgemm<<<2048, 256, 0, stream>>>(XT, Wh, bpw, out);
}

// Round 7
// 425.651 us; speedup vs baseline: 1.0060x; 1.0060x over previous
//
#include <hip/hip_runtime.h>

typedef _Float16 f16;
typedef _Float16 f16x8 __attribute__((ext_vector_type(8)));
typedef unsigned short u16x8 __attribute__((ext_vector_type(8)));
typedef float f32x4 __attribute__((ext_vector_type(4)));

#define GLB_AS(p) ((const __attribute__((address_space(1))) unsigned int*)(p))
#define LDS_AS(p) ((__attribute__((address_space(3))) unsigned int*)(p))

// ---------------------------------------------------------------------------
// Kernel S: w_pw fp32 -> fp16 (single rail; threshold 1.25e-2 allows it)
// ---------------------------------------------------------------------------
__global__ __launch_bounds__(256) void whalf(const float* __restrict__ w,
                                             f16* __restrict__ wh) {
  int i = blockIdx.x * 256 + threadIdx.x;  // 65536 total
  wh[i] = (f16)w[i];
}

// ---------------------------------------------------------------------------
// Kernel A: fused depthwise (stage1 3x3 d1 -> branch conv) per channel.
// HT = halo of the *second* conv: 0 (ch 0-63, passthrough), 3 (ch 64-127,
// 3x3 dil3), 6 (ch 128-255, 5x5 dil3).  One block = one (plane, 32x32 tile).
// LDS row stride 52 floats (52 % 32banks = 20 -> the 8 orow groups in a wave
// land on 8 distinct bank starts; was 48 = 8-way conflict, 3.1e7 cycles).
// Writes xc (fp16) planar [b][c][h][w] into Xp (scratch in d_out 2nd half).
// ---------------------------------------------------------------------------
template <int HT>
__global__ __launch_bounds__(256) void dwfuse(
    const float* __restrict__ x, const float* __restrict__ w0,
    const float* __restrict__ b0, const float* __restrict__ w1,
    const float* __restrict__ b1, const float* __restrict__ w2,
    const float* __restrict__ b2, f16* __restrict__ Xp) {
  constexpr int S2 = 32 + 2 * HT;         // t (=x0) tile incl. halo
  constexpr int S1 = S2 + 2;              // x tile incl. halo
  constexpr int PO = (HT == 6) ? 2 : 0;   // pad offset so branch f4 reads align
  constexpr int QW = (S2 + 3) / 4;        // quads per t row
  constexpr int LW = 52;                  // LDS row stride (floats)
  __shared__ float xs[S1 * LW];
  __shared__ float ts[S2 * LW];
  const int tid = threadIdx.x;

  int b, ch;
  if constexpr (HT == 0) { b = blockIdx.z >> 6; ch = (int)(blockIdx.z & 63); }
  else if constexpr (HT == 3) { b = blockIdx.z >> 6; ch = 64 + (int)(blockIdx.z & 63); }
  else { b = blockIdx.z >> 7; ch = 128 + (int)(blockIdx.z & 127); }
  const int plane = b * 256 + ch;
  const int R0 = (int)blockIdx.y * 32, C0 = (int)blockIdx.x * 32;
  const float* xp = x + (size_t)plane * 16384;

  float W0[9];
#pragma unroll
  for (int k = 0; k < 9; ++k) W0[k] = w0[ch * 9 + k];
  const float B0 = b0[ch];

  // ---- phase 1: load x tile (+halo) into LDS, zero outside image ----
  const int br = R0 - HT - 1, bc = C0 - HT - 1;
  for (int i = tid; i < S1 * S1; i += 256) {
    int r = i / S1, c = i - r * S1;
    int gr = br + r, gc = bc + c;
    float v = 0.f;
    if ((unsigned)gr < 128u && (unsigned)gc < 128u) v = xp[gr * 128 + gc];
    xs[r * LW + c] = v;
  }
  __syncthreads();

  // ---- phase 2: t = conv3x3(x)+b0 on S2 x S2 (zeroed outside image: x0's
  //      zero-padding semantics for the branch conv) ----
  for (int q = tid; q < S2 * QW; q += 256) {
    int r = q / QW, c4 = (q - r * QW) * 4;
    float a0 = 0, a1 = 0, a2 = 0, a3 = 0;
#pragma unroll
    for (int dy = 0; dy < 3; ++dy) {
      const float* row = &xs[(r + dy) * LW + c4];
      float4 qa = *(const float4*)row;
      float4 qb = *(const float4*)(row + 4);
      float wA = W0[dy * 3 + 0], wB = W0[dy * 3 + 1], wC = W0[dy * 3 + 2];
      a0 += wA * qa.x + wB * qa.y + wC * qa.z;
      a1 += wA * qa.y + wB * qa.z + wC * qa.w;
      a2 += wA * qa.z + wB * qa.w + wC * qb.x;
      a3 += wA * qa.w + wB * qb.x + wC * qb.y;
    }
    int gr = R0 - HT + r;
    int gc = C0 - HT + c4;
    bool rok = (unsigned)gr < 128u;
    float o0 = (rok && (unsigned)(gc + 0) < 128u) ? a0 + B0 : 0.f;
    float o1 = (rok && (unsigned)(gc + 1) < 128u) ? a1 + B0 : 0.f;
    float o2 = (rok && (unsigned)(gc + 2) < 128u) ? a2 + B0 : 0.f;
    float o3 = (rok && (unsigned)(gc + 3) < 128u) ? a3 + B0 : 0.f;
    float* tp = &ts[r * LW + c4 + PO];
    tp[0] = o0; tp[1] = o1; tp[2] = o2; tp[3] = o3;
  }
  __syncthreads();

  // ---- phase 3: branch conv, 4 horizontally-adjacent outputs per thread ----
  const int orow = tid >> 3;        // 0..31
  const int oc4 = (tid & 7) << 2;   // 0,4,..,28
  float o0, o1, o2, o3;
  if constexpr (HT == 0) {
    float4 qa = *(const float4*)&ts[orow * LW + oc4];
    o0 = qa.x; o1 = qa.y; o2 = qa.z; o3 = qa.w;
  } else if constexpr (HT == 3) {
    const int wi = ch & 63;
    float W1[9];
#pragma unroll
    for (int k = 0; k < 9; ++k) W1[k] = w1[wi * 9 + k];
    o0 = o1 = o2 = o3 = b1[wi];
#pragma unroll
    for (int dy = 0; dy < 3; ++dy) {
      const float* row = &ts[(orow + 3 * dy) * LW + oc4];
      float4 qa = *(const float4*)row;
      float4 qb = *(const float4*)(row + 4);
      float4 qc = *(const float4*)(row + 8);
      float v[12] = {qa.x, qa.y, qa.z, qa.w, qb.x, qb.y, qb.z, qb.w,
                     qc.x, qc.y, qc.z, qc.w};
#pragma unroll
      for (int dx = 0; dx < 3; ++dx) {
        float w = W1[dy * 3 + dx];
        o0 += w * v[3 * dx + 0];
        o1 += w * v[3 * dx + 1];
        o2 += w * v[3 * dx + 2];
        o3 += w * v[3 * dx + 3];
      }
    }
  } else {
    const int wi = ch & 63;   // g2: ch-128, g3: ch-192 -> both = ch&63
    float W2[25];
#pragma unroll
    for (int k = 0; k < 25; ++k) W2[k] = w2[wi * 25 + k];
    o0 = o1 = o2 = o3 = b2[wi];
#pragma unroll
    for (int dy = 0; dy < 5; ++dy) {
      const float* row = &ts[(orow + 3 * dy) * LW + oc4];
      float4 qa = *(const float4*)(row + 0);
      float4 qb = *(const float4*)(row + 4);
      float4 qc = *(const float4*)(row + 8);
      float4 qd = *(const float4*)(row + 12);
      float4 qe = *(const float4*)(row + 16);
      float v[20] = {qa.x, qa.y, qa.z, qa.w, qb.x, qb.y, qb.z, qb.w,
                     qc.x, qc.y, qc.z, qc.w, qd.x, qd.y, qd.z, qd.w,
                     qe.x, qe.y, qe.z, qe.w};
#pragma unroll
      for (int dx = 0; dx < 5; ++dx) {
        float w = W2[dy * 5 + dx];
        o0 += w * v[3 * dx + 2];
        o1 += w * v[3 * dx + 3];
        o2 += w * v[3 * dx + 4];
        o3 += w * v[3 * dx + 5];
      }
    }
  }
  const size_t oidx =
      (size_t)plane * 16384 + (size_t)(R0 + orow) * 128 + (C0 + oc4);
  union { f16 h[4]; uint2 u; } ph;
  ph.h[0] = (f16)o0; ph.h[1] = (f16)o1; ph.h[2] = (f16)o2; ph.h[3] = (f16)o3;
  *(uint2*)&Xp[oidx] = ph.u;
}

// ---------------------------------------------------------------------------
// Kernel T: transpose xc planar [b][c][16384px] -> XT [b][16384px][256c].
// 64c x 64px tile via LDS (u32 slots, pad-65 => <=2-way banks), coalesced
// 16B loads/stores both sides.
// ---------------------------------------------------------------------------
__global__ __launch_bounds__(256) void t_xpose(const f16* __restrict__ Xp,
                                               f16* __restrict__ XT) {
  __shared__ unsigned ld[64 * 65];
  const int t = threadIdx.x;
  const int b = (int)blockIdx.z, c0 = (int)blockIdx.y << 6,
            p0 = (int)blockIdx.x << 6;
  {
    const int r = t >> 2, ch = (t & 3) << 4;
    const f16* src = Xp + (((size_t)b * 256 + c0 + r) << 14) + p0 + ch;
    u16x8 v0 = *(const u16x8*)src;
    u16x8 v1 = *(const u16x8*)(src + 8);
#pragma unroll
    for (int i = 0; i < 8; ++i) ld[r * 65 + ch + i] = v0[i];
#pragma unroll
    for (int i = 0; i < 8; ++i) ld[r * 65 + ch + 8 + i] = v1[i];
  }
  __syncthreads();
  {
    const int pr = t >> 2, cc = (t & 3) << 4;
    u16x8 w0, w1;
#pragma unroll
    for (int i = 0; i < 8; ++i) w0[i] = (unsigned short)ld[(cc + i) * 65 + pr];
#pragma unroll
    for (int i = 0; i < 8; ++i)
      w1[i] = (unsigned short)ld[(cc + 8 + i) * 65 + pr];
    f16* dst = XT + (((size_t)b * 16384 + p0 + pr) << 8) + c0 + cc;
    *(u16x8*)dst = w0;
    *(u16x8*)(dst + 8) = w1;
  }
}

// ---------------------------------------------------------------------------
// Kernel B: pointwise as fp16 MFMA GEMM, m97 pattern + BK=64 double buffer.
// y[o,px] = sum_c W[o,c] * XT[px,c].  Block: 128o x 128px, 4 waves (64x64),
// K=256 in 4 steps of 64.  OPERAND-SWAPPED: A = XT tile (M=px), B = W rows
// (N=o) -> D[row=px][col=o], so each lane holds 4 CONSECUTIVE px at fixed o
// and the epilogue is 16 dwordx4 stores (was 64 scalar).
// XT staged via global_load_lds, linear dest; LDS row = 128 B (8 octs of
// 8 f16); oct o stored at slot o ^ (px&7), same XOR on the pre-swizzled
// global source and the ds_read side (G21); 8 lanes/oct -> 8 distinct slots
// => 2-way banks (free).  T3-minimum pipeline: stage ks+1 before computing
// ks, single __syncthreads per step.
// ---------------------------------------------------------------------------
__global__ __launch_bounds__(256) void pwgemm(const f16* __restrict__ XT,
                                              const f16* __restrict__ Wh,
                                              const float* __restrict__ bpw,
                                              float* __restrict__ out) {
  __shared__ f16 smem[16384];  // 32 KB: 2 buffers x (128 px x 64 k)
  const int tid = threadIdx.x, lane = tid & 63, wid = tid >> 6;
  const int bx = (int)blockIdx.x;
  const int nblk = bx >> 1;           // pixel-block; bx pair shares XT tile
  const int m0 = (bx & 1) << 7;       // o-half: 0 or 128
  const int bb = nblk >> 7;           // batch
  const int p0 = (nblk & 127) << 7;   // pixel base within plane

  // staging: round rnd (0..3): LDS byte L = rnd*4096 + tid*16 ->
  // px = rnd*32 + (tid>>3), slot s = tid&7 holds logical oct o = s ^ (px&7)
  const int spx = tid >> 3;                  // px within round
  const int so = (tid & 7) ^ (spx & 7);      // rnd*32 doesn't change px&7
  const f16* xb = XT + (((size_t)bb * 16384 + p0 + spx) << 8) + so * 8;
  const unsigned lwb =
      __builtin_amdgcn_readfirstlane((unsigned)(wid * 1024));

  const int wo = (wid >> 1) << 6, wp = (wid & 1) << 6;  // wave 64o x 64px tile
  const int brow_ = lane & 15, boct = lane >> 4;
  const f16* wrow = Wh + (m0 + wo + brow_) * 256 + boct * 8;

  // A-frag (X from LDS) byte offsets: for (mf, k2): logical oct = k2*4 + boct
  unsigned aoff[4][2];
#pragma unroll
  for (int mf = 0; mf < 4; ++mf) {
    int px = wp + mf * 16 + (lane & 15);
#pragma unroll
    for (int k2 = 0; k2 < 2; ++k2)
      aoff[mf][k2] =
          (unsigned)(px * 128 + ((((k2 << 2) + boct) ^ (px & 7)) << 4));
  }

  f32x4 acc[4][4] = {};  // [px-frag mf][o-frag nf]

  // prologue: stage step 0 into buffer 0
#pragma unroll
  for (int rnd = 0; rnd < 4; ++rnd)
    __builtin_amdgcn_global_load_lds(
        GLB_AS(xb + rnd * 8192),
        LDS_AS((char*)smem + rnd * 4096 + lwb), 16, 0, 0);
  __syncthreads();

  for (int ks = 0; ks < 4; ++ks) {
    const int cur = ks & 1;
    if (ks < 3) {  // stage next step into the other buffer
#pragma unroll
      for (int rnd = 0; rnd < 4; ++rnd)
        __builtin_amdgcn_global_load_lds(
            GLB_AS(xb + rnd * 8192 + (ks + 1) * 64),
            LDS_AS((char*)smem + (cur ^ 1) * 16384 + rnd * 4096 + lwb), 16, 0,
            0);
    }
    f16x8 bw[4][2], ax[4][2];
#pragma unroll
    for (int nf = 0; nf < 4; ++nf)
#pragma unroll
      for (int k2 = 0; k2 < 2; ++k2)
        bw[nf][k2] = *(const f16x8*)(wrow + nf * 16 * 256 + ks * 64 + k2 * 32);
#pragma unroll
    for (int mf = 0; mf < 4; ++mf)
#pragma unroll
      for (int k2 = 0; k2 < 2; ++k2)
        ax[mf][k2] =
            *(const f16x8*)((const char*)smem + cur * 16384 + aoff[mf][k2]);

#pragma unroll
    for (int k2 = 0; k2 < 2; ++k2)
#pragma unroll
      for (int mf = 0; mf < 4; ++mf)
#pragma unroll
        for (int nf = 0; nf < 4; ++nf)
          acc[mf][nf] = __builtin_amdgcn_mfma_f32_16x16x32_f16(
              ax[mf][k2], bw[nf][k2], acc[mf][nf], 0, 0, 0);
    // one barrier per step: drains my reads (lgkm) + my next-step staging
    // (vmcnt) before any wave overwrites buf cur^1 / reads it
    __syncthreads();
  }

  // ---- epilogue: D[row=px][col=o]: px = wp+mf*16+(lane>>4)*4+r,
  //      o = wo+nf*16+(lane&15).  float4 store of 4 consecutive px. ----
  float bias_o[4];
#pragma unroll
  for (int nf = 0; nf < 4; ++nf)
    bias_o[nf] = bpw[m0 + wo + nf * 16 + (lane & 15)];

  float* op = out + (size_t)bb * 4194304;
  const int px0 = p0 + wp + ((lane >> 4) << 2);
#pragma unroll
  for (int mf = 0; mf < 4; ++mf) {
#pragma unroll
    for (int nf = 0; nf < 4; ++nf) {
      const int o = m0 + wo + nf * 16 + (lane & 15);
      float4 v;
      v.x = acc[mf][nf][0] + bias_o[nf];
      v.y = acc[mf][nf][1] + bias_o[nf];
      v.z = acc[mf][nf][2] + bias_o[nf];
      v.w = acc[mf][nf][3] + bias_o[nf];
      *(float4*)&op[(size_t)o * 16384 + px0 + mf * 16] = v;
    }
  }
}

// ---------------------------------------------------------------------------
extern "C" void kernel_launch(void* const* d_in, const int* in_sizes, int n_in,
                              void* d_out, int out_size, void* d_ws,
                              size_t ws_size, hipStream_t stream) {
  const float* x = (const float*)d_in[0];
  const float* w0 = (const float*)d_in[1];
  const float* b0 = (const float*)d_in[2];
  const float* w1 = (const float*)d_in[3];
  const float* b1 = (const float*)d_in[4];
  const float* w2 = (const float*)d_in[5];
  const float* b2 = (const float*)d_in[6];
  const float* wpw = (const float*)d_in[7];
  const float* bpw = (const float*)d_in[8];
  float* out = (float*)d_out;

  // scratch plan (ws need: 64.125 MiB):
  //   Xp (planar fp16 xc, 64 MiB)  -> d_out second half (read only by t_xpose,
  //                                    which completes before pwgemm writes)
  //   XT (transposed fp16, 64 MiB) -> ws[0:64M]
  //   Wh (fp16 w_pw, 128 KiB)      -> ws[64M:]
  f16* Xp = (f16*)((char*)d_out + 67108864);
  f16* XT = (f16*)d_ws;
  f16* Wh = (f16*)((char*)d_ws + 67108864);

  whalf<<<256, 256, 0, stream>>>(wpw, Wh);
  dwfuse<0><<<dim3(4, 4, 512), 256, 0, stream>>>(x, w0, b0, w1, b1, w2, b2, Xp);
  dwfuse<3><<<dim3(4, 4, 512), 256, 0, stream>>>(x, w0, b0, w1, b1, w2, b2, Xp);
  dwfuse<6><<<dim3(4, 4, 1024), 256, 0, stream>>>(x, w0, b0, w1, b1, w2, b2,
                                                  Xp);
  t_xpose<<<dim3(256, 4, 8), 256, 0, stream>>>(Xp, XT);
  pwgemm<<<2048, 256, 0, stream>>>(XT, Wh, bpw, out);
}

// Round 9
// 399.419 us; speedup vs baseline: 1.0721x; 1.0657x over previous
//
#include <hip/hip_runtime.h>

typedef _Float16 f16;
typedef _Float16 f16x8 __attribute__((ext_vector_type(8)));
typedef unsigned short u16x8 __attribute__((ext_vector_type(8)));
typedef float f32x4 __attribute__((ext_vector_type(4)));

#define GLB_AS(p) ((const __attribute__((address_space(1))) unsigned int*)(p))
#define LDS_AS(p) ((__attribute__((address_space(3))) unsigned int*)(p))

// ---------------------------------------------------------------------------
// Kernel S: w_pw fp32 -> fp16 (single rail; threshold 1.25e-2 allows it)
// ---------------------------------------------------------------------------
__global__ __launch_bounds__(256) void whalf(const float* __restrict__ w,
                                             f16* __restrict__ wh) {
  int i = blockIdx.x * 256 + threadIdx.x;  // 65536 total
  wh[i] = (f16)w[i];
}

// ---------------------------------------------------------------------------
// Kernel A: fused depthwise (stage1 3x3 d1 -> branch conv) per channel.
// HT = halo of the *second* conv: 0 (ch 0-63, passthrough), 3 (ch 64-127,
// 3x3 dil3), 6 (ch 128-255, 5x5 dil3).  One block = one (plane, 32x32 tile).
// CONFLICT-FREE REWRITE (r7): phases 2/3 are 1 px/thread with consecutive-
// lane cols; every LDS access is a wave-wide stride-1 ds_read_b32/write_b32
// at a compile-time offset (m136: <=2 lanes/bank = free).  The previous
// float4-window version kept 52% of runtime in bank-conflict serialization
// (3.4e7 cycles) because 16B-aligned b128 lanes can only start on banks
// = 0 mod 4, regardless of row-stride padding.
// Writes xc (fp16) planar [b][c][h][w] into Xp (scratch in d_out 2nd half).
// ---------------------------------------------------------------------------
template <int HT>
__global__ __launch_bounds__(256) void dwfuse(
    const float* __restrict__ x, const float* __restrict__ w0,
    const float* __restrict__ b0, const float* __restrict__ w1,
    const float* __restrict__ b1, const float* __restrict__ w2,
    const float* __restrict__ b2, f16* __restrict__ Xp) {
  constexpr int S2 = 32 + 2 * HT;  // t (=x0) tile incl. halo (padding == HT)
  constexpr int S1 = S2 + 2;       // x tile incl. halo
  constexpr int LW = 52;           // LDS row stride (words); >= S1
  __shared__ float xs[S1 * LW];
  __shared__ float ts[S2 * LW];
  const int tid = threadIdx.x;

  int b, ch;
  if constexpr (HT == 0) { b = blockIdx.z >> 6; ch = (int)(blockIdx.z & 63); }
  else if constexpr (HT == 3) { b = blockIdx.z >> 6; ch = 64 + (int)(blockIdx.z & 63); }
  else { b = blockIdx.z >> 7; ch = 128 + (int)(blockIdx.z & 127); }
  const int plane = b * 256 + ch;
  const int R0 = (int)blockIdx.y * 32, C0 = (int)blockIdx.x * 32;
  const float* xp = x + (size_t)plane * 16384;

  float W0[9];
#pragma unroll
  for (int k = 0; k < 9; ++k) W0[k] = w0[ch * 9 + k];
  const float B0 = b0[ch];

  // ---- phase 1: load x tile (+halo) into LDS, zero outside image ----
  const int br = R0 - HT - 1, bc = C0 - HT - 1;
  for (int i = tid; i < S1 * S1; i += 256) {
    int r = i / S1, c = i - r * S1;
    int gr = br + r, gc = bc + c;
    float v = 0.f;
    if ((unsigned)gr < 128u && (unsigned)gc < 128u) v = xp[gr * 128 + gc];
    xs[r * LW + c] = v;
  }
  __syncthreads();

  // ---- phase 2: t = conv3x3(x)+b0 on S2 x S2, zeroed outside image (x0's
  //      zero-padding semantics).  1 px/thread, scalar taps, lanes at
  //      consecutive c -> stride-1 LDS (conflict-free). ----
  for (int i = tid; i < S2 * S2; i += 256) {
    int r = i / S2, c = i - r * S2;
    const float* base = &xs[r * LW + c];
    float a = B0;
#pragma unroll
    for (int dy = 0; dy < 3; ++dy)
#pragma unroll
      for (int dx = 0; dx < 3; ++dx) a += W0[dy * 3 + dx] * base[dy * LW + dx];
    int gr = R0 - HT + r, gc = C0 - HT + c;
    float o = ((unsigned)gr < 128u && (unsigned)gc < 128u) ? a : 0.f;
    ts[r * LW + c] = o;
  }
  __syncthreads();

  // ---- phase 3: branch conv, 1 px/thread (r = i>>5, c = i&31), taps at
  //      ts[(r+3dy)*LW + c+3dx] (padding == HT makes this uniform). ----
  if constexpr (HT == 0) {
#pragma unroll
    for (int k = 0; k < 4; ++k) {
      int i = tid + k * 256;
      int r = i >> 5, c = i & 31;
      float o = ts[r * LW + c];
      Xp[(size_t)plane * 16384 + (size_t)(R0 + r) * 128 + (C0 + c)] = (f16)o;
    }
  } else if constexpr (HT == 3) {
    const int wi = ch & 63;
    float W1[9];
#pragma unroll
    for (int k = 0; k < 9; ++k) W1[k] = w1[wi * 9 + k];
    const float B1 = b1[wi];
#pragma unroll
    for (int k = 0; k < 4; ++k) {
      int i = tid + k * 256;
      int r = i >> 5, c = i & 31;
      const float* base = &ts[r * LW + c];
      float o = B1;
#pragma unroll
      for (int dy = 0; dy < 3; ++dy)
#pragma unroll
        for (int dx = 0; dx < 3; ++dx)
          o += W1[dy * 3 + dx] * base[3 * dy * LW + 3 * dx];
      Xp[(size_t)plane * 16384 + (size_t)(R0 + r) * 128 + (C0 + c)] = (f16)o;
    }
  } else {
    const int wi = ch & 63;  // g2: ch-128, g3: ch-192 -> both = ch&63
    float W2[25];
#pragma unroll
    for (int k = 0; k < 25; ++k) W2[k] = w2[wi * 25 + k];
    const float B2 = b2[wi];
#pragma unroll
    for (int k = 0; k < 4; ++k) {
      int i = tid + k * 256;
      int r = i >> 5, c = i & 31;
      const float* base = &ts[r * LW + c];
      float o = B2;
#pragma unroll
      for (int dy = 0; dy < 5; ++dy)
#pragma unroll
        for (int dx = 0; dx < 5; ++dx)
          o += W2[dy * 5 + dx] * base[3 * dy * LW + 3 * dx];
      Xp[(size_t)plane * 16384 + (size_t)(R0 + r) * 128 + (C0 + c)] = (f16)o;
    }
  }
}

// ---------------------------------------------------------------------------
// Kernel T: transpose xc planar [b][c][16384px] -> XT [b][16384px][256c].
// 64c x 64px tile via LDS (u32 slots, pad-65 => <=2-way banks), coalesced
// 16B loads/stores both sides.
// ---------------------------------------------------------------------------
__global__ __launch_bounds__(256) void t_xpose(const f16* __restrict__ Xp,
                                               f16* __restrict__ XT) {
  __shared__ unsigned ld[64 * 65];
  const int t = threadIdx.x;
  const int b = (int)blockIdx.z, c0 = (int)blockIdx.y << 6,
            p0 = (int)blockIdx.x << 6;
  {
    const int r = t >> 2, ch = (t & 3) << 4;
    const f16* src = Xp + (((size_t)b * 256 + c0 + r) << 14) + p0 + ch;
    u16x8 v0 = *(const u16x8*)src;
    u16x8 v1 = *(const u16x8*)(src + 8);
#pragma unroll
    for (int i = 0; i < 8; ++i) ld[r * 65 + ch + i] = v0[i];
#pragma unroll
    for (int i = 0; i < 8; ++i) ld[r * 65 + ch + 8 + i] = v1[i];
  }
  __syncthreads();
  {
    const int pr = t >> 2, cc = (t & 3) << 4;
    u16x8 w0, w1;
#pragma unroll
    for (int i = 0; i < 8; ++i) w0[i] = (unsigned short)ld[(cc + i) * 65 + pr];
#pragma unroll
    for (int i = 0; i < 8; ++i)
      w1[i] = (unsigned short)ld[(cc + 8 + i) * 65 + pr];
    f16* dst = XT + (((size_t)b * 16384 + p0 + pr) << 8) + c0 + cc;
    *(u16x8*)dst = w0;
    *(u16x8*)(dst + 8) = w1;
  }
}

// ---------------------------------------------------------------------------
// Kernel B: pointwise as fp16 MFMA GEMM, m97 pattern + BK=64 double buffer.
// y[o,px] = sum_c W[o,c] * XT[px,c].  Block: 128o x 128px, 4 waves (64x64),
// K=256 in 4 steps of 64.  OPERAND-SWAPPED: A = XT tile (M=px), B = W rows
// (N=o) -> D[row=px][col=o], so each lane holds 4 CONSECUTIVE px at fixed o
// and the epilogue is 16 dwordx4 stores.
// XT staged via global_load_lds, linear dest; LDS row = 128 B (8 octs of
// 8 f16); oct o stored at slot o ^ (px&7), same XOR on the pre-swizzled
// global source and the ds_read side (G21).
// XCD-PAIR SWIZZLE (r8): wg = (bid&7)*256 + (bid>>3) (bijective, 2048=8*256)
// -> each XCD gets a contiguous 256-chunk, so the two blocks sharing an XT
// tile (wg=2k,2k+1) co-reside on one XCD and share its L2 (T1/m204).
// ---------------------------------------------------------------------------
__global__ __launch_bounds__(256) void pwgemm(const f16* __restrict__ XT,
                                              const f16* __restrict__ Wh,
                                              const float* __restrict__ bpw,
                                              float* __restrict__ out) {
  __shared__ f16 smem[16384];  // 32 KB: 2 buffers x (128 px x 64 k)
  const int tid = threadIdx.x, lane = tid & 63, wid = tid >> 6;
  const int bid = (int)blockIdx.x;
  const int wg = ((bid & 7) << 8) + (bid >> 3);  // XCD-chunked, bijective
  const int nblk = wg >> 1;           // pixel-block; wg pair shares XT tile
  const int m0 = (wg & 1) << 7;       // o-half: 0 or 128
  const int bb = nblk >> 7;           // batch
  const int p0 = (nblk & 127) << 7;   // pixel base within plane

  // staging: round rnd (0..3): LDS byte L = rnd*4096 + tid*16 ->
  // px = rnd*32 + (tid>>3), slot s = tid&7 holds logical oct o = s ^ (px&7)
  const int spx = tid >> 3;                  // px within round
  const int so = (tid & 7) ^ (spx & 7);      // rnd*32 doesn't change px&7
  const f16* xb = XT + (((size_t)bb * 16384 + p0 + spx) << 8) + so * 8;
  const unsigned lwb =
      __builtin_amdgcn_readfirstlane((unsigned)(wid * 1024));

  const int wo = (wid >> 1) << 6, wp = (wid & 1) << 6;  // wave 64o x 64px tile
  const int brow_ = lane & 15, boct = lane >> 4;
  const f16* wrow = Wh + (m0 + wo + brow_) * 256 + boct * 8;

  // A-frag (X from LDS) byte offsets: for (mf, k2): logical oct = k2*4 + boct
  unsigned aoff[4][2];
#pragma unroll
  for (int mf = 0; mf < 4; ++mf) {
    int px = wp + mf * 16 + (lane & 15);
#pragma unroll
    for (int k2 = 0; k2 < 2; ++k2)
      aoff[mf][k2] =
          (unsigned)(px * 128 + ((((k2 << 2) + boct) ^ (px & 7)) << 4));
  }

  f32x4 acc[4][4] = {};  // [px-frag mf][o-frag nf]

  // prologue: stage step 0 into buffer 0
#pragma unroll
  for (int rnd = 0; rnd < 4; ++rnd)
    __builtin_amdgcn_global_load_lds(
        GLB_AS(xb + rnd * 8192),
        LDS_AS((char*)smem + rnd * 4096 + lwb), 16, 0, 0);
  __syncthreads();

  for (int ks = 0; ks < 4; ++ks) {
    const int cur = ks & 1;
    if (ks < 3) {  // stage next step into the other buffer
#pragma unroll
      for (int rnd = 0; rnd < 4; ++rnd)
        __builtin_amdgcn_global_load_lds(
            GLB_AS(xb + rnd * 8192 + (ks + 1) * 64),
            LDS_AS((char*)smem + (cur ^ 1) * 16384 + rnd * 4096 + lwb), 16, 0,
            0);
    }
    f16x8 bw[4][2], ax[4][2];
#pragma unroll
    for (int nf = 0; nf < 4; ++nf)
#pragma unroll
      for (int k2 = 0; k2 < 2; ++k2)
        bw[nf][k2] = *(const f16x8*)(wrow + nf * 16 * 256 + ks * 64 + k2 * 32);
#pragma unroll
    for (int mf = 0; mf < 4; ++mf)
#pragma unroll
      for (int k2 = 0; k2 < 2; ++k2)
        ax[mf][k2] =
            *(const f16x8*)((const char*)smem + cur * 16384 + aoff[mf][k2]);

#pragma unroll
    for (int k2 = 0; k2 < 2; ++k2)
#pragma unroll
      for (int mf = 0; mf < 4; ++mf)
#pragma unroll
        for (int nf = 0; nf < 4; ++nf)
          acc[mf][nf] = __builtin_amdgcn_mfma_f32_16x16x32_f16(
              ax[mf][k2], bw[nf][k2], acc[mf][nf], 0, 0, 0);
    // one barrier per step: drains my reads (lgkm) + my next-step staging
    // (vmcnt) before any wave overwrites buf cur^1 / reads it
    __syncthreads();
  }

  // ---- epilogue: D[row=px][col=o]: px = wp+mf*16+(lane>>4)*4+r,
  //      o = wo+nf*16+(lane&15).  float4 store of 4 consecutive px. ----
  float bias_o[4];
#pragma unroll
  for (int nf = 0; nf < 4; ++nf)
    bias_o[nf] = bpw[m0 + wo + nf * 16 + (lane & 15)];

  float* op = out + (size_t)bb * 4194304;
  const int px0 = p0 + wp + ((lane >> 4) << 2);
#pragma unroll
  for (int mf = 0; mf < 4; ++mf) {
#pragma unroll
    for (int nf = 0; nf < 4; ++nf) {
      const int o = m0 + wo + nf * 16 + (lane & 15);
      float4 v;
      v.x = acc[mf][nf][0] + bias_o[nf];
      v.y = acc[mf][nf][1] + bias_o[nf];
      v.z = acc[mf][nf][2] + bias_o[nf];
      v.w = acc[mf][nf][3] + bias_o[nf];
      *(float4*)&op[(size_t)o * 16384 + px0 + mf * 16] = v;
    }
  }
}

// ---------------------------------------------------------------------------
extern "C" void kernel_launch(void* const* d_in, const int* in_sizes, int n_in,
                              void* d_out, int out_size, void* d_ws,
                              size_t ws_size, hipStream_t stream) {
  const float* x = (const float*)d_in[0];
  const float* w0 = (const float*)d_in[1];
  const float* b0 = (const float*)d_in[2];
  const float* w1 = (const float*)d_in[3];
  const float* b1 = (const float*)d_in[4];
  const float* w2 = (const float*)d_in[5];
  const float* b2 = (const float*)d_in[6];
  const float* wpw = (const float*)d_in[7];
  const float* bpw = (const float*)d_in[8];
  float* out = (float*)d_out;

  // scratch plan (ws need: 64.125 MiB):
  //   Xp (planar fp16 xc, 64 MiB)  -> d_out second half (read only by t_xpose,
  //                                    which completes before pwgemm writes)
  //   XT (transposed fp16, 64 MiB) -> ws[0:64M]
  //   Wh (fp16 w_pw, 128 KiB)      -> ws[64M:]
  f16* Xp = (f16*)((char*)d_out + 67108864);
  f16* XT = (f16*)d_ws;
  f16* Wh = (f16*)((char*)d_ws + 67108864);

  whalf<<<256, 256, 0, stream>>>(wpw, Wh);
  dwfuse<0><<<dim3(4, 4, 512), 256, 0, stream>>>(x, w0, b0, w1, b1, w2, b2, Xp);
  dwfuse<3><<<dim3(4, 4, 512), 256, 0, stream>>>(x, w0, b0, w1, b1, w2, b2, Xp);
  dwfuse<6><<<dim3(4, 4, 1024), 256, 0, stream>>>(x, w0, b0, w1, b1, w2, b2,
                                                  Xp);
  t_xpose<<<dim3(256, 4, 8), 256, 0, stream>>>(Xp, XT);
  pwgemm<<<2048, 256, 0, stream>>>(XT, Wh, bpw, out);
}